// Round 1
// baseline (3201.970 us; speedup 1.0000x reference)
//
#include <hip/hip_runtime.h>
#include <stdint.h>

// ---------------------------------------------------------------------------
// JAX threefry2x32 (20 rounds), matching jax/_src/prng.py
// ---------------------------------------------------------------------------
struct SnnKeys { unsigned int k0[30]; unsigned int k1[30]; };

__host__ __device__ static inline void tf2x32(unsigned int k0, unsigned int k1,
                                              unsigned int& x0, unsigned int& x1) {
  unsigned int ks2 = k0 ^ k1 ^ 0x1BD11BDAu;
#define TF_RND(r) { x0 += x1; x1 = (x1 << (r)) | (x1 >> (32 - (r))); x1 ^= x0; }
  x0 += k0; x1 += k1;
  TF_RND(13) TF_RND(15) TF_RND(26) TF_RND(6)
  x0 += k1; x1 += ks2 + 1u;
  TF_RND(17) TF_RND(29) TF_RND(16) TF_RND(24)
  x0 += ks2; x1 += k0 + 2u;
  TF_RND(13) TF_RND(15) TF_RND(26) TF_RND(6)
  x0 += k0; x1 += k1 + 3u;
  TF_RND(17) TF_RND(29) TF_RND(16) TF_RND(24)
  x0 += k1; x1 += ks2 + 4u;
  TF_RND(13) TF_RND(15) TF_RND(26) TF_RND(6)
  x0 += ks2; x1 += k0 + 5u;
#undef TF_RND
}

// ---------------------------------------------------------------------------
// Stage 0: 2x2 average pool  x(4,24,602,602) -> xp(4,24,301,301)
// ---------------------------------------------------------------------------
#define POOL_N (4 * 24 * 301 * 301)

__global__ __launch_bounds__(256) void k_pool(const float* __restrict__ x,
                                              float* __restrict__ xp) {
  int i = blockIdx.x * 256 + threadIdx.x;
  if (i >= POOL_N) return;
  int j = i % 301;
  int rest = i / 301;
  int r = rest % 301;
  int bc = rest / 301;
  const float* src = x + ((size_t)bc * 602 + 2 * r) * 602 + 2 * j;
  float2 a = *(const float2*)src;
  float2 b = *(const float2*)(src + 602);
  xp[i] = 0.25f * ((a.x + a.y) + (b.x + b.y));
}

// ---------------------------------------------------------------------------
// conv1: xp as (4,1,24,301,301), w1(16,1,3,15,15), stride 2 -> h1(4,16,11,144,144), relu
// grid (9,9,44) block 256.  wave -> 4 co, thread -> 4 spatial (16x16 tile)
// ---------------------------------------------------------------------------
__global__ __launch_bounds__(256) void k_conv1(const float* __restrict__ xp,
                                               const float* __restrict__ w1,
                                               const float* __restrict__ b1,
                                               float* __restrict__ h1) {
  __shared__ alignas(16) float in_t[45 * 46];
  __shared__ alignas(16) float wt[225 * 16];   // [k][co]
  const int tid = threadIdx.x;
  const int wave = tid >> 6, lane = tid & 63;
  const int sy = lane >> 3, sx = lane & 7;
  const int cob = wave * 4;
  const int b = blockIdx.z / 11, d = blockIdx.z % 11;
  const int h0 = blockIdx.y * 16, w0 = blockIdx.x * 16;

  float acc[4][4];
#pragma unroll
  for (int c = 0; c < 4; ++c)
#pragma unroll
    for (int q = 0; q < 4; ++q) acc[c][q] = 0.0f;

  for (int kd = 0; kd < 3; ++kd) {
    __syncthreads();
    const int dd = 2 * d + kd;
    const float* src = xp + ((size_t)(b * 24 + dd) * 301) * 301;
    for (int i = tid; i < 45 * 45; i += 256) {
      int r = i / 45, c = i - r * 45;
      in_t[r * 46 + c] = src[(2 * h0 + r) * 301 + (2 * w0 + c)];
    }
    {
      const int co = tid & 15;
      const float* wsrc = w1 + ((size_t)co * 3 + kd) * 225;
      for (int k = tid >> 4; k < 225; k += 16) wt[k * 16 + co] = wsrc[k];
    }
    __syncthreads();
    for (int kh = 0; kh < 15; ++kh) {
      const float* inrow0 = &in_t[(2 * sy + kh) * 46 + 2 * sx];
      const float* inrow1 = inrow0 + 16 * 46;
      const float* wrow = &wt[kh * 15 * 16 + cob];
#pragma unroll
      for (int kw = 0; kw < 15; ++kw) {
        float v[4];
        v[0] = inrow0[kw];
        v[1] = inrow0[kw + 16];
        v[2] = inrow1[kw];
        v[3] = inrow1[kw + 16];
        const float4 wv = *(const float4*)&wrow[kw * 16];
        float wz[4] = {wv.x, wv.y, wv.z, wv.w};
#pragma unroll
        for (int c = 0; c < 4; ++c)
#pragma unroll
          for (int q = 0; q < 4; ++q) acc[c][q] += v[q] * wz[c];
      }
    }
  }
#pragma unroll
  for (int q = 0; q < 4; ++q) {
    int hh = h0 + sy + 8 * (q >> 1);
    int ww = w0 + sx + 8 * (q & 1);
#pragma unroll
    for (int c = 0; c < 4; ++c) {
      int co = cob + c;
      float v = acc[c][q] + b1[co];
      h1[(((size_t)(b * 16 + co) * 11 + d) * 144 + hh) * 144 + ww] = fmaxf(v, 0.0f);
    }
  }
}

// ---------------------------------------------------------------------------
// conv2: h1(4,16,11,144,144), w2(32,16,3,15,15) -> h2(4,32,5,65,65), relu
// grid (5,5,20) block 256.  wave -> 8 co, thread -> 4 spatial (16x16 tile)
// ---------------------------------------------------------------------------
__global__ __launch_bounds__(256) void k_conv2(const float* __restrict__ h1,
                                               const float* __restrict__ w2,
                                               const float* __restrict__ b2,
                                               float* __restrict__ h2) {
  __shared__ alignas(16) float in_t[45 * 46];
  __shared__ alignas(16) float wt[225 * 32];   // [k][co]
  const int tid = threadIdx.x;
  const int wave = tid >> 6, lane = tid & 63;
  const int sy = lane >> 3, sx = lane & 7;
  const int cob = wave * 8;
  const int b = blockIdx.z / 5, d = blockIdx.z % 5;
  const int h0 = blockIdx.y * 16, w0 = blockIdx.x * 16;

  float acc[8][4];
#pragma unroll
  for (int c = 0; c < 8; ++c)
#pragma unroll
    for (int q = 0; q < 4; ++q) acc[c][q] = 0.0f;

  for (int ci = 0; ci < 16; ++ci) {
    for (int kd = 0; kd < 3; ++kd) {
      __syncthreads();
      const int dd = 2 * d + kd;
      const float* src = h1 + (((size_t)(b * 16 + ci) * 11 + dd) * 144) * 144;
      for (int i = tid; i < 45 * 45; i += 256) {
        int r = i / 45, c = i - r * 45;
        int gr = 2 * h0 + r, gc = 2 * w0 + c;
        float v = 0.0f;
        if (gr < 144 && gc < 144) v = src[gr * 144 + gc];
        in_t[r * 46 + c] = v;
      }
      {
        const int co = tid & 31;
        const float* wsrc = w2 + ((size_t)(co * 16 + ci) * 3 + kd) * 225;
        for (int k = tid >> 5; k < 225; k += 8) wt[k * 32 + co] = wsrc[k];
      }
      __syncthreads();
      for (int kh = 0; kh < 15; ++kh) {
        const float* inrow0 = &in_t[(2 * sy + kh) * 46 + 2 * sx];
        const float* inrow1 = inrow0 + 16 * 46;
        const float* wrow = &wt[kh * 15 * 32 + cob];
#pragma unroll
        for (int kw = 0; kw < 15; ++kw) {
          float v[4];
          v[0] = inrow0[kw];
          v[1] = inrow0[kw + 16];
          v[2] = inrow1[kw];
          v[3] = inrow1[kw + 16];
          const float4 wv0 = *(const float4*)&wrow[kw * 32];
          const float4 wv1 = *(const float4*)&wrow[kw * 32 + 4];
          float wz[8] = {wv0.x, wv0.y, wv0.z, wv0.w, wv1.x, wv1.y, wv1.z, wv1.w};
#pragma unroll
          for (int c = 0; c < 8; ++c)
#pragma unroll
            for (int q = 0; q < 4; ++q) acc[c][q] += v[q] * wz[c];
        }
      }
    }
  }
#pragma unroll
  for (int q = 0; q < 4; ++q) {
    int hh = h0 + sy + 8 * (q >> 1);
    int ww = w0 + sx + 8 * (q & 1);
    if (hh < 65 && ww < 65) {
#pragma unroll
      for (int c = 0; c < 8; ++c) {
        int co = cob + c;
        float v = acc[c][q] + b2[co];
        h2[(((size_t)(b * 32 + co) * 5 + d) * 65 + hh) * 65 + ww] = fmaxf(v, 0.0f);
      }
    }
  }
}

// ---------------------------------------------------------------------------
// conv3: h2(4,32,5,65,65), w3(16,32,3,15,15) -> partial sums (no bias/relu here)
// split ci into 2 groups -> two partial buffers (deterministic, no atomics)
// grid (4,4,16) block 256: bz = ((b*2+d)*2+cig). wave -> 4 co, thread -> 1 spatial (8x8 tile)
// ---------------------------------------------------------------------------
__global__ __launch_bounds__(256) void k_conv3(const float* __restrict__ h2,
                                               const float* __restrict__ w3,
                                               float* __restrict__ h3base) {
  __shared__ alignas(16) float in_t[29 * 30];
  __shared__ alignas(16) float wt[225 * 16];   // [k][co]
  const int tid = threadIdx.x;
  const int wave = tid >> 6, lane = tid & 63;
  const int sy = lane >> 3, sx = lane & 7;
  const int cob = wave * 4;
  const int bz = blockIdx.z;
  const int cig = bz & 1, d = (bz >> 1) & 1, b = bz >> 2;
  const int h0 = blockIdx.y * 8, w0 = blockIdx.x * 8;
  float* dst = h3base + (size_t)cig * 86528;

  float acc[4] = {0.0f, 0.0f, 0.0f, 0.0f};

  for (int cil = 0; cil < 16; ++cil) {
    const int ci = cig * 16 + cil;
    for (int kd = 0; kd < 3; ++kd) {
      __syncthreads();
      const int dd = 2 * d + kd;
      const float* src = h2 + (((size_t)(b * 32 + ci) * 5 + dd) * 65) * 65;
      for (int i = tid; i < 29 * 29; i += 256) {
        int r = i / 29, c = i - r * 29;
        int gr = 2 * h0 + r, gc = 2 * w0 + c;
        float v = 0.0f;
        if (gr < 65 && gc < 65) v = src[gr * 65 + gc];
        in_t[r * 30 + c] = v;
      }
      {
        const int co = tid & 15;
        const float* wsrc = w3 + ((size_t)(co * 32 + ci) * 3 + kd) * 225;
        for (int k = tid >> 4; k < 225; k += 16) wt[k * 16 + co] = wsrc[k];
      }
      __syncthreads();
      for (int kh = 0; kh < 15; ++kh) {
        const float* inrow = &in_t[(2 * sy + kh) * 30 + 2 * sx];
        const float* wrow = &wt[kh * 15 * 16 + cob];
#pragma unroll
        for (int kw = 0; kw < 15; ++kw) {
          float v = inrow[kw];
          const float4 wv = *(const float4*)&wrow[kw * 16];
          acc[0] += v * wv.x;
          acc[1] += v * wv.y;
          acc[2] += v * wv.z;
          acc[3] += v * wv.w;
        }
      }
    }
  }
  int hh = h0 + sy, ww = w0 + sx;
  if (hh < 26 && ww < 26) {
#pragma unroll
    for (int c = 0; c < 4; ++c) {
      dst[(((size_t)(b * 16 + cob + c) * 2 + d) * 26 + hh) * 26 + ww] = acc[c];
    }
  }
}

// ---------------------------------------------------------------------------
// spikes: x_snn = relu(h3a+h3b+bias); r = threefry-uniform; spk = (0.5x > r)
// grid (338, 30) block 256
// ---------------------------------------------------------------------------
__global__ __launch_bounds__(256) void k_spike(const float* __restrict__ h3a,
                                               const float* __restrict__ h3b,
                                               const float* __restrict__ b3,
                                               float* __restrict__ spk,
                                               SnnKeys keys) {
  int p = blockIdx.x * 256 + threadIdx.x;   // < 86528
  int t = blockIdx.y;
  int j = p % 21632;
  int co = j / 1352;                        // 1352 = 2*26*26
  float x = h3a[p] + h3b[p] + b3[co];
  x = fmaxf(x, 0.0f);
  unsigned int x0 = 0u, x1 = (unsigned int)p;
  tf2x32(keys.k0[t], keys.k1[t], x0, x1);
  unsigned int bits = x0 ^ x1;              // partitionable 32-bit path
  float r = __uint_as_float((bits >> 9) | 0x3f800000u) - 1.0f;
  spk[(size_t)t * 86528 + p] = (0.5f * x > r) ? 1.0f : 0.0f;
}

// ---------------------------------------------------------------------------
// fc1 GEMM: inc_part[kc][m=(t*4+b)][n] = sum_k spk[m][k]*fc1_w[n][k]  (K split 13x1664)
// grid (16 nt, 13 kc), block (8,16)=128. thread tile 8m x 4n.
// ---------------------------------------------------------------------------
__global__ __launch_bounds__(128) void k_fc1(const float* __restrict__ spk,
                                             const float* __restrict__ fc1w,
                                             float* __restrict__ incp) {
  __shared__ alignas(16) float slds[16][128];
  __shared__ alignas(16) float wlds[16][32];
  const int tx = threadIdx.x;               // 0..7
  const int ty = threadIdx.y;               // 0..15
  const int tid = ty * 8 + tx;
  const int nt = blockIdx.x;                // 0..15
  const int kc = blockIdx.y;                // 0..12
  const int k0base = kc * 1664;

  float acc[8][4];
#pragma unroll
  for (int mi = 0; mi < 8; ++mi)
#pragma unroll
    for (int ni = 0; ni < 4; ++ni) acc[mi][ni] = 0.0f;

  for (int kb = 0; kb < 1664; kb += 16) {
    const int k0 = k0base + kb;
    __syncthreads();
    {
      int m = tid;  // 0..127
      float4 v[4] = {{0,0,0,0},{0,0,0,0},{0,0,0,0},{0,0,0,0}};
      if (m < 120) {
        const float4* s = (const float4*)(spk + (size_t)m * 21632 + k0);
        v[0] = s[0]; v[1] = s[1]; v[2] = s[2]; v[3] = s[3];
      }
#pragma unroll
      for (int q = 0; q < 4; ++q) {
        slds[4 * q + 0][m] = v[q].x;
        slds[4 * q + 1][m] = v[q].y;
        slds[4 * q + 2][m] = v[q].z;
        slds[4 * q + 3][m] = v[q].w;
      }
    }
    for (int e = tid; e < 512; e += 128) {
      int n = e >> 4, kk = e & 15;
      wlds[kk][n] = fc1w[(size_t)(nt * 32 + n) * 21632 + k0 + kk];
    }
    __syncthreads();
#pragma unroll
    for (int kk = 0; kk < 16; ++kk) {
      const float4 wv = *(const float4*)&wlds[kk][tx * 4];
      const float4 s0 = *(const float4*)&slds[kk][ty * 8];
      const float4 s1 = *(const float4*)&slds[kk][ty * 8 + 4];
      float sv[8] = {s0.x, s0.y, s0.z, s0.w, s1.x, s1.y, s1.z, s1.w};
      float wz[4] = {wv.x, wv.y, wv.z, wv.w};
#pragma unroll
      for (int mi = 0; mi < 8; ++mi)
#pragma unroll
        for (int ni = 0; ni < 4; ++ni) acc[mi][ni] += sv[mi] * wz[ni];
    }
  }
#pragma unroll
  for (int mi = 0; mi < 8; ++mi) {
    int m = ty * 8 + mi;
    if (m < 120) {
      float4 o = {acc[mi][0], acc[mi][1], acc[mi][2], acc[mi][3]};
      *(float4*)&incp[((size_t)kc * 120 + m) * 512 + nt * 32 + tx * 4] = o;
    }
  }
}

// ---------------------------------------------------------------------------
// sequential membrane scan per (b,n): fire/reset, emit spike counts
// ---------------------------------------------------------------------------
__global__ __launch_bounds__(256) void k_scan(const float* __restrict__ incp,
                                              const float* __restrict__ fc1b,
                                              float* __restrict__ cnt) {
  int i = blockIdx.x * 256 + threadIdx.x;   // 0..2047
  int b = i >> 9, n = i & 511;
  float bias = fc1b[n];
  float m0 = 0.0f, c = 0.0f;
  for (int t = 0; t < 30; ++t) {
    int m = t * 4 + b;
    float s = bias;
    for (int kc = 0; kc < 13; ++kc) s += incp[((size_t)kc * 120 + m) * 512 + n];
    m0 += s;
    if (m0 > 1.0f) { c += 1.0f; m0 = 0.0f; }
  }
  cnt[i] = c;
}

// ---------------------------------------------------------------------------
// m1[b][o] = 30*fc2_b[o] + sum_n cnt[b][n]*fc2_w[o][n]
// ---------------------------------------------------------------------------
__global__ __launch_bounds__(256) void k_final(const float* __restrict__ cnt,
                                               const float* __restrict__ fc2w,
                                               const float* __restrict__ fc2b,
                                               float* __restrict__ out) {
  int o = threadIdx.x;
  if (o >= 216) return;
  int b = o / 54, oo = o - b * 54;
  const float* w = fc2w + (size_t)oo * 512;
  const float* c = cnt + (size_t)b * 512;
  float s = 0.0f;
  for (int n = 0; n < 512; ++n) s += c[n] * w[n];
  out[o] = s + 30.0f * fc2b[oo];
}

// ---------------------------------------------------------------------------
extern "C" void kernel_launch(void* const* d_in, const int* in_sizes, int n_in,
                              void* d_out, int out_size, void* d_ws, size_t ws_size,
                              hipStream_t stream) {
  (void)in_sizes; (void)n_in; (void)out_size; (void)ws_size;
  const float* x    = (const float*)d_in[0];
  const float* w1   = (const float*)d_in[1];
  const float* b1   = (const float*)d_in[2];
  const float* w2   = (const float*)d_in[3];
  const float* b2   = (const float*)d_in[4];
  const float* w3   = (const float*)d_in[5];
  const float* b3   = (const float*)d_in[6];
  const float* fc1w = (const float*)d_in[7];
  const float* fc1b = (const float*)d_in[8];
  const float* fc2w = (const float*)d_in[9];
  const float* fc2b = (const float*)d_in[10];
  float* out = (float*)d_out;
  float* ws  = (float*)d_ws;

  // workspace layout (floats); peak requirement = xp+h1 = 23,295,840 fl = 93.2 MB
  float* xp   = ws;                       // 8,697,696   (dead after conv1)
  float* h1   = ws + 8697696;             // 14,598,144  (dead after conv2)
  float* h2   = ws;                       // 2,704,000   (reuses xp)
  float* h3   = ws + 8697696;             // 2*86,528 partials (reuses h1)
  float* spk  = h3 + 2 * 86528;           // 2,595,840
  float* incp = spk + 2595840;            // 13*61,440 = 798,720
  float* cnt  = incp + 13 * 61440;        // 2,048

  // host-side threefry: seed 42 -> key (0,42); foldlike split (partitionable)
  SnnKeys keys;
  for (int t = 0; t < 30; ++t) {
    unsigned int a = 0u, bb = (unsigned int)t;
    tf2x32(0u, 42u, a, bb);
    keys.k0[t] = a; keys.k1[t] = bb;
  }

  k_pool <<<(POOL_N + 255) / 256, 256, 0, stream>>>(x, xp);
  k_conv1<<<dim3(9, 9, 44),  256, 0, stream>>>(xp, w1, b1, h1);
  k_conv2<<<dim3(5, 5, 20),  256, 0, stream>>>(h1, w2, b2, h2);
  k_conv3<<<dim3(4, 4, 16),  256, 0, stream>>>(h2, w3, h3);
  k_spike<<<dim3(338, 30),   256, 0, stream>>>(h3, h3 + 86528, b3, spk, keys);
  k_fc1  <<<dim3(16, 13), dim3(8, 16), 0, stream>>>(spk, fc1w, incp);
  k_scan <<<8, 256, 0, stream>>>(incp, fc1b, cnt);
  k_final<<<1, 256, 0, stream>>>(cnt, fc2w, fc2b, out);
}

// Round 2
// 2444.532 us; speedup vs baseline: 1.3099x; 1.3099x over previous
//
#include <hip/hip_runtime.h>
#include <stdint.h>

// ---------------------------------------------------------------------------
// JAX threefry2x32 (20 rounds), matching jax/_src/prng.py
// ---------------------------------------------------------------------------
struct SnnKeys { unsigned int k0[30]; unsigned int k1[30]; };

__host__ __device__ static inline void tf2x32(unsigned int k0, unsigned int k1,
                                              unsigned int& x0, unsigned int& x1) {
  unsigned int ks2 = k0 ^ k1 ^ 0x1BD11BDAu;
#define TF_RND(r) { x0 += x1; x1 = (x1 << (r)) | (x1 >> (32 - (r))); x1 ^= x0; }
  x0 += k0; x1 += k1;
  TF_RND(13) TF_RND(15) TF_RND(26) TF_RND(6)
  x0 += k1; x1 += ks2 + 1u;
  TF_RND(17) TF_RND(29) TF_RND(16) TF_RND(24)
  x0 += ks2; x1 += k0 + 2u;
  TF_RND(13) TF_RND(15) TF_RND(26) TF_RND(6)
  x0 += k0; x1 += k1 + 3u;
  TF_RND(17) TF_RND(29) TF_RND(16) TF_RND(24)
  x0 += k1; x1 += ks2 + 4u;
  TF_RND(13) TF_RND(15) TF_RND(26) TF_RND(6)
  x0 += ks2; x1 += k0 + 5u;
#undef TF_RND
}

// ---------------------------------------------------------------------------
// Stage 0: 2x2 average pool  x(4,24,602,602) -> xp(4,24,301,301)
// ---------------------------------------------------------------------------
#define POOL_N (4 * 24 * 301 * 301)

__global__ __launch_bounds__(256) void k_pool(const float* __restrict__ x,
                                              float* __restrict__ xp) {
  int i = blockIdx.x * 256 + threadIdx.x;
  if (i >= POOL_N) return;
  int j = i % 301;
  int rest = i / 301;
  int r = rest % 301;
  int bc = rest / 301;
  const float* src = x + ((size_t)bc * 602 + 2 * r) * 602 + 2 * j;
  float2 a = *(const float2*)src;
  float2 b = *(const float2*)(src + 602);
  xp[i] = 0.25f * ((a.x + a.y) + (b.x + b.y));
}

// ---------------------------------------------------------------------------
// conv1: xp as (4,1,24,301,301), w1(16,1,3,15,15), stride 2 -> h1(4,16,11,144,144), relu
// grid (9,9,44) block 256.  wave -> 4 co, thread -> 4 spatial (16x16 tile)
// LDS input tile de-interleaved by x-parity (pitch 25) -> max 2-way bank alias (free)
// ---------------------------------------------------------------------------
__global__ __launch_bounds__(256) void k_conv1(const float* __restrict__ xp,
                                               const float* __restrict__ w1,
                                               const float* __restrict__ b1,
                                               float* __restrict__ h1) {
  __shared__ alignas(16) float in_e[45 * 25];
  __shared__ alignas(16) float in_o[45 * 25];
  __shared__ alignas(16) float wt[225 * 16];   // [k][co]
  const int tid = threadIdx.x;
  const int wave = tid >> 6, lane = tid & 63;
  const int sy = lane >> 3, sx = lane & 7;
  const int cob = wave * 4;
  const int b = blockIdx.z / 11, d = blockIdx.z % 11;
  const int h0 = blockIdx.y * 16, w0 = blockIdx.x * 16;

  float acc[4][4];
#pragma unroll
  for (int c = 0; c < 4; ++c)
#pragma unroll
    for (int q = 0; q < 4; ++q) acc[c][q] = 0.0f;

  for (int kd = 0; kd < 3; ++kd) {
    __syncthreads();
    const int dd = 2 * d + kd;
    const float* src = xp + ((size_t)(b * 24 + dd) * 301) * 301;
    for (int i = tid; i < 45 * 45; i += 256) {
      int r = i / 45, c = i - r * 45;
      float v = src[(2 * h0 + r) * 301 + (2 * w0 + c)];
      float* dstp = (c & 1) ? in_o : in_e;
      dstp[r * 25 + (c >> 1)] = v;
    }
    {
      const int co = tid & 15;
      const float* wsrc = w1 + ((size_t)co * 3 + kd) * 225;
      for (int k = tid >> 4; k < 225; k += 16) wt[k * 16 + co] = wsrc[k];
    }
    __syncthreads();
    for (int kh = 0; kh < 15; ++kh) {
      const float* pe = &in_e[(2 * sy + kh) * 25 + sx];
      const float* po = &in_o[(2 * sy + kh) * 25 + sx];
      const float* wrow = &wt[kh * 15 * 16 + cob];
#pragma unroll
      for (int j = 0; j < 8; ++j) {       // even kw = 2j
        float vv[4];
        vv[0] = pe[j];
        vv[1] = pe[j + 8];
        vv[2] = pe[j + 16 * 25];
        vv[3] = pe[j + 16 * 25 + 8];
        const float4 wv = *(const float4*)&wrow[(2 * j) * 16];
        float wz[4] = {wv.x, wv.y, wv.z, wv.w};
#pragma unroll
        for (int c = 0; c < 4; ++c)
#pragma unroll
          for (int q = 0; q < 4; ++q) acc[c][q] += vv[q] * wz[c];
      }
#pragma unroll
      for (int j = 0; j < 7; ++j) {       // odd kw = 2j+1
        float vv[4];
        vv[0] = po[j];
        vv[1] = po[j + 8];
        vv[2] = po[j + 16 * 25];
        vv[3] = po[j + 16 * 25 + 8];
        const float4 wv = *(const float4*)&wrow[(2 * j + 1) * 16];
        float wz[4] = {wv.x, wv.y, wv.z, wv.w};
#pragma unroll
        for (int c = 0; c < 4; ++c)
#pragma unroll
          for (int q = 0; q < 4; ++q) acc[c][q] += vv[q] * wz[c];
      }
    }
  }
#pragma unroll
  for (int q = 0; q < 4; ++q) {
    int hh = h0 + sy + 8 * (q >> 1);
    int ww = w0 + sx + 8 * (q & 1);
#pragma unroll
    for (int c = 0; c < 4; ++c) {
      int co = cob + c;
      float v = acc[c][q] + b1[co];
      h1[(((size_t)(b * 16 + co) * 11 + d) * 144 + hh) * 144 + ww] = fmaxf(v, 0.0f);
    }
  }
}

// ---------------------------------------------------------------------------
// conv2: h1(4,16,11,144,144), w2(32,16,3,15,15) -> partials (2 ci-groups), no bias/relu
// grid (5,5,40) block 256: z = (b*5+d)*2+cig. wave -> 8 co, thread -> 4 spatial.
// ---------------------------------------------------------------------------
__global__ __launch_bounds__(256) void k_conv2(const float* __restrict__ h1,
                                               const float* __restrict__ w2,
                                               float* __restrict__ h2p) {
  __shared__ alignas(16) float in_e[45 * 25];
  __shared__ alignas(16) float in_o[45 * 25];
  __shared__ alignas(16) float wt[225 * 32];   // [k][co]
  const int tid = threadIdx.x;
  const int wave = tid >> 6, lane = tid & 63;
  const int sy = lane >> 3, sx = lane & 7;
  const int cob = wave * 8;
  const int bz = blockIdx.z;
  const int cig = bz & 1;
  const int t5 = bz >> 1;
  const int b = t5 / 5, d = t5 % 5;
  const int h0 = blockIdx.y * 16, w0 = blockIdx.x * 16;

  float acc[8][4];
#pragma unroll
  for (int c = 0; c < 8; ++c)
#pragma unroll
    for (int q = 0; q < 4; ++q) acc[c][q] = 0.0f;

  for (int cil = 0; cil < 8; ++cil) {
    const int ci = cig * 8 + cil;
    for (int kd = 0; kd < 3; ++kd) {
      __syncthreads();
      const int dd = 2 * d + kd;
      const float* src = h1 + (((size_t)(b * 16 + ci) * 11 + dd) * 144) * 144;
      for (int i = tid; i < 45 * 45; i += 256) {
        int r = i / 45, c = i - r * 45;
        int gr = 2 * h0 + r, gc = 2 * w0 + c;
        float v = 0.0f;
        if (gr < 144 && gc < 144) v = src[gr * 144 + gc];
        float* dstp = (c & 1) ? in_o : in_e;
        dstp[r * 25 + (c >> 1)] = v;
      }
      {
        const int co = tid & 31;
        const float* wsrc = w2 + ((size_t)(co * 16 + ci) * 3 + kd) * 225;
        for (int k = tid >> 5; k < 225; k += 8) wt[k * 32 + co] = wsrc[k];
      }
      __syncthreads();
      for (int kh = 0; kh < 15; ++kh) {
        const float* pe = &in_e[(2 * sy + kh) * 25 + sx];
        const float* po = &in_o[(2 * sy + kh) * 25 + sx];
        const float* wrow = &wt[kh * 15 * 32 + cob];
#pragma unroll
        for (int j = 0; j < 8; ++j) {     // even kw = 2j
          float vv[4];
          vv[0] = pe[j];
          vv[1] = pe[j + 8];
          vv[2] = pe[j + 16 * 25];
          vv[3] = pe[j + 16 * 25 + 8];
          const float4 wa = *(const float4*)&wrow[(2 * j) * 32];
          const float4 wb = *(const float4*)&wrow[(2 * j) * 32 + 4];
          float wz[8] = {wa.x, wa.y, wa.z, wa.w, wb.x, wb.y, wb.z, wb.w};
#pragma unroll
          for (int c = 0; c < 8; ++c)
#pragma unroll
            for (int q = 0; q < 4; ++q) acc[c][q] += vv[q] * wz[c];
        }
#pragma unroll
        for (int j = 0; j < 7; ++j) {     // odd kw = 2j+1
          float vv[4];
          vv[0] = po[j];
          vv[1] = po[j + 8];
          vv[2] = po[j + 16 * 25];
          vv[3] = po[j + 16 * 25 + 8];
          const float4 wa = *(const float4*)&wrow[(2 * j + 1) * 32];
          const float4 wb = *(const float4*)&wrow[(2 * j + 1) * 32 + 4];
          float wz[8] = {wa.x, wa.y, wa.z, wa.w, wb.x, wb.y, wb.z, wb.w};
#pragma unroll
          for (int c = 0; c < 8; ++c)
#pragma unroll
            for (int q = 0; q < 4; ++q) acc[c][q] += vv[q] * wz[c];
        }
      }
    }
  }
#pragma unroll
  for (int q = 0; q < 4; ++q) {
    int hh = h0 + sy + 8 * (q >> 1);
    int ww = w0 + sx + 8 * (q & 1);
    if (hh < 65 && ww < 65) {
#pragma unroll
      for (int c = 0; c < 8; ++c) {
        int co = cob + c;
        h2p[(size_t)cig * 2704000 +
            (((size_t)(b * 32 + co) * 5 + d) * 65 + hh) * 65 + ww] = acc[c][q];
      }
    }
  }
}

// combine conv2 partials + bias + relu
__global__ __launch_bounds__(256) void k_h2fix(const float* __restrict__ p,
                                               const float* __restrict__ b2,
                                               float* __restrict__ h2) {
  int i = blockIdx.x * 256 + threadIdx.x;
  if (i >= 2704000) return;
  int co = (i / 21125) & 31;               // 21125 = 5*65*65
  float v = p[i] + p[2704000 + i] + b2[co];
  h2[i] = fmaxf(v, 0.0f);
}

// ---------------------------------------------------------------------------
// conv3: h2(4,32,5,65,65), w3(16,32,3,15,15) -> partials (4 ci-groups)
// grid (4,4,32) block 256: z = b*8 + d*4 + cig. wave -> 4 co, thread -> 1 spatial.
// ---------------------------------------------------------------------------
__global__ __launch_bounds__(256) void k_conv3(const float* __restrict__ h2,
                                               const float* __restrict__ w3,
                                               float* __restrict__ h3p) {
  __shared__ alignas(16) float in_e[29 * 25];
  __shared__ alignas(16) float in_o[29 * 25];
  __shared__ alignas(16) float wt[225 * 16];   // [k][co]
  const int tid = threadIdx.x;
  const int wave = tid >> 6, lane = tid & 63;
  const int sy = lane >> 3, sx = lane & 7;
  const int cob = wave * 4;
  const int bz = blockIdx.z;
  const int cig = bz & 3, d = (bz >> 2) & 1, b = bz >> 3;
  const int h0 = blockIdx.y * 8, w0 = blockIdx.x * 8;
  float* dst = h3p + (size_t)cig * 86528;

  float acc[4] = {0.0f, 0.0f, 0.0f, 0.0f};

  for (int cil = 0; cil < 8; ++cil) {
    const int ci = cig * 8 + cil;
    for (int kd = 0; kd < 3; ++kd) {
      __syncthreads();
      const int dd = 2 * d + kd;
      const float* src = h2 + (((size_t)(b * 32 + ci) * 5 + dd) * 65) * 65;
      for (int i = tid; i < 29 * 29; i += 256) {
        int r = i / 29, c = i - r * 29;
        int gr = 2 * h0 + r, gc = 2 * w0 + c;
        float v = 0.0f;
        if (gr < 65 && gc < 65) v = src[gr * 65 + gc];
        float* dstp = (c & 1) ? in_o : in_e;
        dstp[r * 25 + (c >> 1)] = v;
      }
      {
        const int co = tid & 15;
        const float* wsrc = w3 + ((size_t)(co * 32 + ci) * 3 + kd) * 225;
        for (int k = tid >> 4; k < 225; k += 16) wt[k * 16 + co] = wsrc[k];
      }
      __syncthreads();
      for (int kh = 0; kh < 15; ++kh) {
        const float* pe = &in_e[(2 * sy + kh) * 25 + sx];
        const float* po = &in_o[(2 * sy + kh) * 25 + sx];
        const float* wrow = &wt[kh * 15 * 16 + cob];
#pragma unroll
        for (int j = 0; j < 8; ++j) {
          float v = pe[j];
          const float4 wv = *(const float4*)&wrow[(2 * j) * 16];
          acc[0] += v * wv.x; acc[1] += v * wv.y;
          acc[2] += v * wv.z; acc[3] += v * wv.w;
        }
#pragma unroll
        for (int j = 0; j < 7; ++j) {
          float v = po[j];
          const float4 wv = *(const float4*)&wrow[(2 * j + 1) * 16];
          acc[0] += v * wv.x; acc[1] += v * wv.y;
          acc[2] += v * wv.z; acc[3] += v * wv.w;
        }
      }
    }
  }
  int hh = h0 + sy, ww = w0 + sx;
  if (hh < 26 && ww < 26) {
#pragma unroll
    for (int c = 0; c < 4; ++c) {
      dst[(((size_t)(b * 16 + cob + c) * 2 + d) * 26 + hh) * 26 + ww] = acc[c];
    }
  }
}

// ---------------------------------------------------------------------------
// spikes: x_snn = relu(sum of 4 partials + bias); threefry uniform; binary spike
// grid (338, 30) block 256
// ---------------------------------------------------------------------------
__global__ __launch_bounds__(256) void k_spike(const float* __restrict__ h3p,
                                               const float* __restrict__ b3,
                                               float* __restrict__ spk,
                                               SnnKeys keys) {
  int p = blockIdx.x * 256 + threadIdx.x;   // < 86528
  int t = blockIdx.y;
  int j = p % 21632;
  int co = j / 1352;                        // 1352 = 2*26*26
  float x = h3p[p] + h3p[86528 + p] + h3p[2 * 86528 + p] + h3p[3 * 86528 + p] + b3[co];
  x = fmaxf(x, 0.0f);
  unsigned int x0 = 0u, x1 = (unsigned int)p;
  tf2x32(keys.k0[t], keys.k1[t], x0, x1);
  unsigned int bits = x0 ^ x1;              // partitionable 32-bit path
  float r = __uint_as_float((bits >> 9) | 0x3f800000u) - 1.0f;
  spk[(size_t)t * 86528 + p] = (0.5f * x > r) ? 1.0f : 0.0f;
}

// ---------------------------------------------------------------------------
// fc1 GEMM: inc_part[kc][m=(t*4+b)][n] = sum_k spk[m][k]*fc1_w[n][k]  (K split 13x1664)
// grid (16 nt, 13 kc), block (8,16)=128. thread tile 8m x 4n.
// ---------------------------------------------------------------------------
__global__ __launch_bounds__(128) void k_fc1(const float* __restrict__ spk,
                                             const float* __restrict__ fc1w,
                                             float* __restrict__ incp) {
  __shared__ alignas(16) float slds[16][128];
  __shared__ alignas(16) float wlds[16][32];
  const int tx = threadIdx.x;               // 0..7
  const int ty = threadIdx.y;               // 0..15
  const int tid = ty * 8 + tx;
  const int nt = blockIdx.x;                // 0..15
  const int kc = blockIdx.y;                // 0..12
  const int k0base = kc * 1664;

  float acc[8][4];
#pragma unroll
  for (int mi = 0; mi < 8; ++mi)
#pragma unroll
    for (int ni = 0; ni < 4; ++ni) acc[mi][ni] = 0.0f;

  for (int kb = 0; kb < 1664; kb += 16) {
    const int k0 = k0base + kb;
    __syncthreads();
    {
      int m = tid;  // 0..127
      float4 v[4] = {{0,0,0,0},{0,0,0,0},{0,0,0,0},{0,0,0,0}};
      if (m < 120) {
        const float4* s = (const float4*)(spk + (size_t)m * 21632 + k0);
        v[0] = s[0]; v[1] = s[1]; v[2] = s[2]; v[3] = s[3];
      }
#pragma unroll
      for (int q = 0; q < 4; ++q) {
        slds[4 * q + 0][m] = v[q].x;
        slds[4 * q + 1][m] = v[q].y;
        slds[4 * q + 2][m] = v[q].z;
        slds[4 * q + 3][m] = v[q].w;
      }
    }
    for (int e = tid; e < 512; e += 128) {
      int n = e >> 4, kk = e & 15;
      wlds[kk][n] = fc1w[(size_t)(nt * 32 + n) * 21632 + k0 + kk];
    }
    __syncthreads();
#pragma unroll
    for (int kk = 0; kk < 16; ++kk) {
      const float4 wv = *(const float4*)&wlds[kk][tx * 4];
      const float4 s0 = *(const float4*)&slds[kk][ty * 8];
      const float4 s1 = *(const float4*)&slds[kk][ty * 8 + 4];
      float sv[8] = {s0.x, s0.y, s0.z, s0.w, s1.x, s1.y, s1.z, s1.w};
      float wz[4] = {wv.x, wv.y, wv.z, wv.w};
#pragma unroll
      for (int mi = 0; mi < 8; ++mi)
#pragma unroll
        for (int ni = 0; ni < 4; ++ni) acc[mi][ni] += sv[mi] * wz[ni];
    }
  }
#pragma unroll
  for (int mi = 0; mi < 8; ++mi) {
    int m = ty * 8 + mi;
    if (m < 120) {
      float4 o = {acc[mi][0], acc[mi][1], acc[mi][2], acc[mi][3]};
      *(float4*)&incp[((size_t)kc * 120 + m) * 512 + nt * 32 + tx * 4] = o;
    }
  }
}

// ---------------------------------------------------------------------------
// sequential membrane scan per (b,n): fire/reset, emit spike counts
// ---------------------------------------------------------------------------
__global__ __launch_bounds__(256) void k_scan(const float* __restrict__ incp,
                                              const float* __restrict__ fc1b,
                                              float* __restrict__ cnt) {
  int i = blockIdx.x * 256 + threadIdx.x;   // 0..2047
  int b = i >> 9, n = i & 511;
  float bias = fc1b[n];
  float m0 = 0.0f, c = 0.0f;
  for (int t = 0; t < 30; ++t) {
    int m = t * 4 + b;
    float s = bias;
    for (int kc = 0; kc < 13; ++kc) s += incp[((size_t)kc * 120 + m) * 512 + n];
    m0 += s;
    if (m0 > 1.0f) { c += 1.0f; m0 = 0.0f; }
  }
  cnt[i] = c;
}

// ---------------------------------------------------------------------------
// m1[b][o] = 30*fc2_b[o] + sum_n cnt[b][n]*fc2_w[o][n]
// ---------------------------------------------------------------------------
__global__ __launch_bounds__(256) void k_final(const float* __restrict__ cnt,
                                               const float* __restrict__ fc2w,
                                               const float* __restrict__ fc2b,
                                               float* __restrict__ out) {
  int o = threadIdx.x;
  if (o >= 216) return;
  int b = o / 54, oo = o - b * 54;
  const float* w = fc2w + (size_t)oo * 512;
  const float* c = cnt + (size_t)b * 512;
  float s = 0.0f;
  for (int n = 0; n < 512; ++n) s += c[n] * w[n];
  out[o] = s + 30.0f * fc2b[oo];
}

// ---------------------------------------------------------------------------
extern "C" void kernel_launch(void* const* d_in, const int* in_sizes, int n_in,
                              void* d_out, int out_size, void* d_ws, size_t ws_size,
                              hipStream_t stream) {
  (void)in_sizes; (void)n_in; (void)out_size; (void)ws_size;
  const float* x    = (const float*)d_in[0];
  const float* w1   = (const float*)d_in[1];
  const float* b1   = (const float*)d_in[2];
  const float* w2   = (const float*)d_in[3];
  const float* b2   = (const float*)d_in[4];
  const float* w3   = (const float*)d_in[5];
  const float* b3   = (const float*)d_in[6];
  const float* fc1w = (const float*)d_in[7];
  const float* fc1b = (const float*)d_in[8];
  const float* fc2w = (const float*)d_in[9];
  const float* fc2b = (const float*)d_in[10];
  float* out = (float*)d_out;
  float* ws  = (float*)d_ws;

  // workspace layout (floats); peak = 8,697,696 + 14,598,144 = 93.2 MB
  float* xp   = ws;                       // 8,697,696   (dead after conv1)
  float* h1   = ws + 8697696;             // 14,598,144  (dead after conv2)
  float* h2p  = ws;                       // 2 x 2,704,000 (reuses xp region)
  float* h2   = ws + 5408000;             // 2,704,000 (ends 8,112,000 < 8,697,696)
  float* h3p  = ws + 8697696;             // 4 x 86,528 (reuses h1 region)
  float* spk  = h3p + 4 * 86528;          // 2,595,840
  float* incp = spk + 2595840;            // 13 x 61,440 = 798,720
  float* cnt  = incp + 13 * 61440;        // 2,048

  // host-side threefry: seed 42 -> key (0,42); partitionable split
  SnnKeys keys;
  for (int t = 0; t < 30; ++t) {
    unsigned int a = 0u, bb = (unsigned int)t;
    tf2x32(0u, 42u, a, bb);
    keys.k0[t] = a; keys.k1[t] = bb;
  }

  k_pool <<<(POOL_N + 255) / 256, 256, 0, stream>>>(x, xp);
  k_conv1<<<dim3(9, 9, 44),  256, 0, stream>>>(xp, w1, b1, h1);
  k_conv2<<<dim3(5, 5, 40),  256, 0, stream>>>(h1, w2, h2p);
  k_h2fix<<<(2704000 + 255) / 256, 256, 0, stream>>>(h2p, b2, h2);
  k_conv3<<<dim3(4, 4, 32),  256, 0, stream>>>(h2, w3, h3p);
  k_spike<<<dim3(338, 30),   256, 0, stream>>>(h3p, b3, spk, keys);
  k_fc1  <<<dim3(16, 13), dim3(8, 16), 0, stream>>>(spk, fc1w, incp);
  k_scan <<<8, 256, 0, stream>>>(incp, fc1b, cnt);
  k_final<<<1, 256, 0, stream>>>(cnt, fc2w, fc2b, out);
}

// Round 3
// 2374.815 us; speedup vs baseline: 1.3483x; 1.0294x over previous
//
#include <hip/hip_runtime.h>
#include <stdint.h>

// ---------------------------------------------------------------------------
// JAX threefry2x32 (20 rounds), matching jax/_src/prng.py
// ---------------------------------------------------------------------------
struct SnnKeys { unsigned int k0[30]; unsigned int k1[30]; };

__host__ __device__ static inline void tf2x32(unsigned int k0, unsigned int k1,
                                              unsigned int& x0, unsigned int& x1) {
  unsigned int ks2 = k0 ^ k1 ^ 0x1BD11BDAu;
#define TF_RND(r) { x0 += x1; x1 = (x1 << (r)) | (x1 >> (32 - (r))); x1 ^= x0; }
  x0 += k0; x1 += k1;
  TF_RND(13) TF_RND(15) TF_RND(26) TF_RND(6)
  x0 += k1; x1 += ks2 + 1u;
  TF_RND(17) TF_RND(29) TF_RND(16) TF_RND(24)
  x0 += ks2; x1 += k0 + 2u;
  TF_RND(13) TF_RND(15) TF_RND(26) TF_RND(6)
  x0 += k0; x1 += k1 + 3u;
  TF_RND(17) TF_RND(29) TF_RND(16) TF_RND(24)
  x0 += k1; x1 += ks2 + 4u;
  TF_RND(13) TF_RND(15) TF_RND(26) TF_RND(6)
  x0 += ks2; x1 += k0 + 5u;
#undef TF_RND
}

// ---------------------------------------------------------------------------
// Stage 0: 2x2 average pool  x(4,24,602,602) -> xp(4,24,301,301)
// ---------------------------------------------------------------------------
#define POOL_N (4 * 24 * 301 * 301)

__global__ __launch_bounds__(256) void k_pool(const float* __restrict__ x,
                                              float* __restrict__ xp) {
  int i = blockIdx.x * 256 + threadIdx.x;
  if (i >= POOL_N) return;
  int j = i % 301;
  int rest = i / 301;
  int r = rest % 301;
  int bc = rest / 301;
  const float* src = x + ((size_t)bc * 602 + 2 * r) * 602 + 2 * j;
  float2 a = *(const float2*)src;
  float2 b = *(const float2*)(src + 602);
  xp[i] = 0.25f * ((a.x + a.y) + (b.x + b.y));
}

// ---------------------------------------------------------------------------
// conv1: xp(4,[1],24,301,301), w1(16,1,3,15,15), stride2 -> h1(4,16,11,144,144), relu
// Flattened-s mapping: plane 144*144=20736 per (b,d). grid (41 stile, 44 b*d).
// 4 waves = 2 co-groups(8co) x 2 s-groups(256 s). lane: 4 s-steps of 64.
// Input LDS: rows 2y0..2y0+24 (25), cols de-interleaved by parity, pitch 152.
// ---------------------------------------------------------------------------
__global__ __launch_bounds__(256) void k_conv1(const float* __restrict__ xp,
                                               const float* __restrict__ w1,
                                               const float* __restrict__ b1,
                                               float* __restrict__ h1) {
  __shared__ alignas(16) float in_e[25 * 152];
  __shared__ alignas(16) float in_o[25 * 152];
  __shared__ alignas(16) float wt[225 * 16];   // [kh*15+kw][co]
  const int tid = threadIdx.x;
  const int wave = tid >> 6, lane = tid & 63;
  const int cog = wave >> 1;                   // 0..1 -> co 8*cog
  const int sg  = wave & 1;                    // 0..1
  const int cob = cog * 8;
  const int bz = blockIdx.y;
  const int b = bz / 11, d = bz % 11;
  const int s0 = blockIdx.x * 512;             // block covers s0..s0+511
  const int y0 = s0 / 144;

  int sq[4], be[4];
  bool vq[4];
#pragma unroll
  for (int q = 0; q < 4; ++q) {
    int s = s0 + sg * 256 + q * 64 + lane;
    vq[q] = (s < 20736);
    int sc = vq[q] ? s : 20735;
    int y = sc / 144;
    int xx = sc - y * 144;
    sq[q] = s;
    be[q] = 2 * (y - y0) * 152 + xx;           // base idx in de-interleaved arrays
  }

  float acc[8][4];
#pragma unroll
  for (int c = 0; c < 8; ++c)
#pragma unroll
    for (int q = 0; q < 4; ++q) acc[c][q] = 0.0f;

  for (int kd = 0; kd < 3; ++kd) {
    __syncthreads();
    const int dd = d + kd;                     // 2*d+kd with stride-2 d? no: d index of h1 depth
    // NOTE: conv1 depth: out d in 0..10, input depth = 2*d+kd
    const int din = 2 * d + kd;
    const float* src = xp + ((size_t)(b * 24 + din) * 301) * 301;
    (void)dd;
    for (int i = tid; i < 25 * 301; i += 256) {
      int r = i / 301, c = i - r * 301;
      int gr = 2 * y0 + r;
      float v = (gr < 301) ? src[gr * 301 + c] : 0.0f;
      float* dstp = (c & 1) ? in_o : in_e;
      dstp[r * 152 + (c >> 1)] = v;
    }
    {
      const int co = tid & 15;
      const float* wsrc = w1 + ((size_t)co * 3 + kd) * 225;
      for (int k = tid >> 4; k < 225; k += 16) wt[k * 16 + co] = wsrc[k];
    }
    __syncthreads();
    for (int kh = 0; kh < 15; ++kh) {
      const float* pe0 = in_e + be[0] + kh * 152;
      const float* pe1 = in_e + be[1] + kh * 152;
      const float* pe2 = in_e + be[2] + kh * 152;
      const float* pe3 = in_e + be[3] + kh * 152;
      const float* po0 = in_o + be[0] + kh * 152;
      const float* po1 = in_o + be[1] + kh * 152;
      const float* po2 = in_o + be[2] + kh * 152;
      const float* po3 = in_o + be[3] + kh * 152;
      const float* we = wt + kh * 240 + cob;
#pragma unroll
      for (int j = 0; j < 8; ++j) {            // even kw = 2j
        float v[4] = {pe0[j], pe1[j], pe2[j], pe3[j]};
        const float4 wa = *(const float4*)&we[(2 * j) * 16];
        const float4 wb = *(const float4*)&we[(2 * j) * 16 + 4];
        float wz[8] = {wa.x, wa.y, wa.z, wa.w, wb.x, wb.y, wb.z, wb.w};
#pragma unroll
        for (int c = 0; c < 8; ++c)
#pragma unroll
          for (int q = 0; q < 4; ++q) acc[c][q] += v[q] * wz[c];
      }
#pragma unroll
      for (int j = 0; j < 7; ++j) {            // odd kw = 2j+1
        float v[4] = {po0[j], po1[j], po2[j], po3[j]};
        const float4 wa = *(const float4*)&we[(2 * j + 1) * 16];
        const float4 wb = *(const float4*)&we[(2 * j + 1) * 16 + 4];
        float wz[8] = {wa.x, wa.y, wa.z, wa.w, wb.x, wb.y, wb.z, wb.w};
#pragma unroll
        for (int c = 0; c < 8; ++c)
#pragma unroll
          for (int q = 0; q < 4; ++q) acc[c][q] += v[q] * wz[c];
      }
    }
  }
#pragma unroll
  for (int q = 0; q < 4; ++q) {
    if (vq[q]) {
#pragma unroll
      for (int c = 0; c < 8; ++c) {
        int co = cob + c;
        float v = acc[c][q] + b1[co];
        h1[((size_t)(b * 16 + co) * 11 + d) * 20736 + sq[q]] = fmaxf(v, 0.0f);
      }
    }
  }
}

// ---------------------------------------------------------------------------
// conv2: h1(4,16,11,144,144), w2(32,16,3,15,15) -> partials (2 ci-groups)
// Flattened-s: plane 65*65=4225 per (b,d). grid (17 stile, 40 = b*d*cig).
// 4 waves = 4 co-groups(8co), all share 256-s range. lane: 4 s-steps of 64.
// Input LDS rows 2y0..2y0+22 (23), parity-de-interleaved pitch 72.
// ---------------------------------------------------------------------------
__global__ __launch_bounds__(256) void k_conv2(const float* __restrict__ h1,
                                               const float* __restrict__ w2,
                                               float* __restrict__ h2p) {
  __shared__ alignas(16) float in_e[23 * 72];
  __shared__ alignas(16) float in_o[23 * 72];
  __shared__ alignas(16) float wt[225 * 32];   // [kh*15+kw][co]
  const int tid = threadIdx.x;
  const int wave = tid >> 6, lane = tid & 63;
  const int cob = wave * 8;
  const int bz = blockIdx.y;
  const int cig = bz & 1;
  const int t5 = bz >> 1;
  const int b = t5 / 5, d = t5 % 5;
  const int s0 = blockIdx.x * 256;
  const int y0 = s0 / 65;

  int sq[4], be[4];
  bool vq[4];
#pragma unroll
  for (int q = 0; q < 4; ++q) {
    int s = s0 + q * 64 + lane;
    vq[q] = (s < 4225);
    int sc = vq[q] ? s : 4224;
    int y = sc / 65;
    int xx = sc - y * 65;
    sq[q] = s;
    be[q] = 2 * (y - y0) * 72 + xx;
  }

  float acc[8][4];
#pragma unroll
  for (int c = 0; c < 8; ++c)
#pragma unroll
    for (int q = 0; q < 4; ++q) acc[c][q] = 0.0f;

  for (int cil = 0; cil < 8; ++cil) {
    const int ci = cig * 8 + cil;
    for (int kd = 0; kd < 3; ++kd) {
      __syncthreads();
      const int din = 2 * d + kd;
      const float* src = h1 + ((size_t)(b * 16 + ci) * 11 + din) * 20736;
      for (int i = tid; i < 23 * 36; i += 256) {
        int r = i / 36, c4 = i - r * 36;
        int gr = 2 * y0 + r;
        float4 v = {0.0f, 0.0f, 0.0f, 0.0f};
        if (gr < 144) v = *(const float4*)(src + gr * 144 + c4 * 4);
        *(float2*)&in_e[r * 72 + 2 * c4] = make_float2(v.x, v.z);
        *(float2*)&in_o[r * 72 + 2 * c4] = make_float2(v.y, v.w);
      }
      {
        const int co = tid & 31;
        const float* wsrc = w2 + ((size_t)(co * 16 + ci) * 3 + kd) * 225;
        for (int k = tid >> 5; k < 225; k += 8) wt[k * 32 + co] = wsrc[k];
      }
      __syncthreads();
      for (int kh = 0; kh < 15; ++kh) {
        const float* pe0 = in_e + be[0] + kh * 72;
        const float* pe1 = in_e + be[1] + kh * 72;
        const float* pe2 = in_e + be[2] + kh * 72;
        const float* pe3 = in_e + be[3] + kh * 72;
        const float* po0 = in_o + be[0] + kh * 72;
        const float* po1 = in_o + be[1] + kh * 72;
        const float* po2 = in_o + be[2] + kh * 72;
        const float* po3 = in_o + be[3] + kh * 72;
        const float* we = wt + kh * 480 + cob;
#pragma unroll
        for (int j = 0; j < 8; ++j) {          // even kw = 2j
          float v[4] = {pe0[j], pe1[j], pe2[j], pe3[j]};
          const float4 wa = *(const float4*)&we[(2 * j) * 32];
          const float4 wb = *(const float4*)&we[(2 * j) * 32 + 4];
          float wz[8] = {wa.x, wa.y, wa.z, wa.w, wb.x, wb.y, wb.z, wb.w};
#pragma unroll
          for (int c = 0; c < 8; ++c)
#pragma unroll
            for (int q = 0; q < 4; ++q) acc[c][q] += v[q] * wz[c];
        }
#pragma unroll
        for (int j = 0; j < 7; ++j) {          // odd kw = 2j+1
          float v[4] = {po0[j], po1[j], po2[j], po3[j]};
          const float4 wa = *(const float4*)&we[(2 * j + 1) * 32];
          const float4 wb = *(const float4*)&we[(2 * j + 1) * 32 + 4];
          float wz[8] = {wa.x, wa.y, wa.z, wa.w, wb.x, wb.y, wb.z, wb.w};
#pragma unroll
          for (int c = 0; c < 8; ++c)
#pragma unroll
            for (int q = 0; q < 4; ++q) acc[c][q] += v[q] * wz[c];
        }
      }
    }
  }
#pragma unroll
  for (int q = 0; q < 4; ++q) {
    if (vq[q]) {
#pragma unroll
      for (int c = 0; c < 8; ++c) {
        int co = cob + c;
        h2p[(size_t)cig * 2704000 +
            ((size_t)(b * 32 + co) * 5 + d) * 4225 + sq[q]] = acc[c][q];
      }
    }
  }
}

// combine conv2 partials + bias + relu
__global__ __launch_bounds__(256) void k_h2fix(const float* __restrict__ p,
                                               const float* __restrict__ b2,
                                               float* __restrict__ h2) {
  int i = blockIdx.x * 256 + threadIdx.x;
  if (i >= 2704000) return;
  int co = (i / 21125) & 31;               // 21125 = 5*65*65
  float v = p[i] + p[2704000 + i] + b2[co];
  h2[i] = fmaxf(v, 0.0f);
}

// ---------------------------------------------------------------------------
// conv3: h2(4,32,5,65,65), w3(16,32,3,15,15) -> partials (4 ci-groups)
// grid (4,4,32) block 256: z = b*8 + d*4 + cig. wave -> 4 co, thread -> 1 spatial.
// ---------------------------------------------------------------------------
__global__ __launch_bounds__(256) void k_conv3(const float* __restrict__ h2,
                                               const float* __restrict__ w3,
                                               float* __restrict__ h3p) {
  __shared__ alignas(16) float in_e[29 * 25];
  __shared__ alignas(16) float in_o[29 * 25];
  __shared__ alignas(16) float wt[225 * 16];   // [k][co]
  const int tid = threadIdx.x;
  const int wave = tid >> 6, lane = tid & 63;
  const int sy = lane >> 3, sx = lane & 7;
  const int cob = wave * 4;
  const int bz = blockIdx.z;
  const int cig = bz & 3, d = (bz >> 2) & 1, b = bz >> 3;
  const int h0 = blockIdx.y * 8, w0 = blockIdx.x * 8;
  float* dst = h3p + (size_t)cig * 86528;

  float acc[4] = {0.0f, 0.0f, 0.0f, 0.0f};

  for (int cil = 0; cil < 8; ++cil) {
    const int ci = cig * 8 + cil;
    for (int kd = 0; kd < 3; ++kd) {
      __syncthreads();
      const int dd = 2 * d + kd;
      const float* src = h2 + (((size_t)(b * 32 + ci) * 5 + dd) * 65) * 65;
      for (int i = tid; i < 29 * 29; i += 256) {
        int r = i / 29, c = i - r * 29;
        int gr = 2 * h0 + r, gc = 2 * w0 + c;
        float v = 0.0f;
        if (gr < 65 && gc < 65) v = src[gr * 65 + gc];
        float* dstp = (c & 1) ? in_o : in_e;
        dstp[r * 25 + (c >> 1)] = v;
      }
      {
        const int co = tid & 15;
        const float* wsrc = w3 + ((size_t)(co * 32 + ci) * 3 + kd) * 225;
        for (int k = tid >> 4; k < 225; k += 16) wt[k * 16 + co] = wsrc[k];
      }
      __syncthreads();
      for (int kh = 0; kh < 15; ++kh) {
        const float* pe = &in_e[(2 * sy + kh) * 25 + sx];
        const float* po = &in_o[(2 * sy + kh) * 25 + sx];
        const float* wrow = &wt[kh * 15 * 16 + cob];
#pragma unroll
        for (int j = 0; j < 8; ++j) {
          float v = pe[j];
          const float4 wv = *(const float4*)&wrow[(2 * j) * 16];
          acc[0] += v * wv.x; acc[1] += v * wv.y;
          acc[2] += v * wv.z; acc[3] += v * wv.w;
        }
#pragma unroll
        for (int j = 0; j < 7; ++j) {
          float v = po[j];
          const float4 wv = *(const float4*)&wrow[(2 * j + 1) * 16];
          acc[0] += v * wv.x; acc[1] += v * wv.y;
          acc[2] += v * wv.z; acc[3] += v * wv.w;
        }
      }
    }
  }
  int hh = h0 + sy, ww = w0 + sx;
  if (hh < 26 && ww < 26) {
#pragma unroll
    for (int c = 0; c < 4; ++c) {
      dst[(((size_t)(b * 16 + cob + c) * 2 + d) * 26 + hh) * 26 + ww] = acc[c];
    }
  }
}

// ---------------------------------------------------------------------------
// spikes: x_snn = relu(sum of 4 partials + bias); threefry uniform; binary spike
// grid (338, 30) block 256
// ---------------------------------------------------------------------------
__global__ __launch_bounds__(256) void k_spike(const float* __restrict__ h3p,
                                               const float* __restrict__ b3,
                                               float* __restrict__ spk,
                                               SnnKeys keys) {
  int p = blockIdx.x * 256 + threadIdx.x;   // < 86528
  int t = blockIdx.y;
  int j = p % 21632;
  int co = j / 1352;                        // 1352 = 2*26*26
  float x = h3p[p] + h3p[86528 + p] + h3p[2 * 86528 + p] + h3p[3 * 86528 + p] + b3[co];
  x = fmaxf(x, 0.0f);
  unsigned int x0 = 0u, x1 = (unsigned int)p;
  tf2x32(keys.k0[t], keys.k1[t], x0, x1);
  unsigned int bits = x0 ^ x1;              // partitionable 32-bit path
  float r = __uint_as_float((bits >> 9) | 0x3f800000u) - 1.0f;
  spk[(size_t)t * 86528 + p] = (0.5f * x > r) ? 1.0f : 0.0f;
}

// ---------------------------------------------------------------------------
// fc1 GEMM: inc_part[kc][m=(t*4+b)][n] = sum_k spk[m][k]*fc1_w[n][k]  (K split 13x1664)
// grid (16 nt, 13 kc), block (8,16)=128. thread tile 8m x 4n.
// ---------------------------------------------------------------------------
__global__ __launch_bounds__(128) void k_fc1(const float* __restrict__ spk,
                                             const float* __restrict__ fc1w,
                                             float* __restrict__ incp) {
  __shared__ alignas(16) float slds[16][128];
  __shared__ alignas(16) float wlds[16][32];
  const int tx = threadIdx.x;               // 0..7
  const int ty = threadIdx.y;               // 0..15
  const int tid = ty * 8 + tx;
  const int nt = blockIdx.x;                // 0..15
  const int kc = blockIdx.y;                // 0..12
  const int k0base = kc * 1664;

  float acc[8][4];
#pragma unroll
  for (int mi = 0; mi < 8; ++mi)
#pragma unroll
    for (int ni = 0; ni < 4; ++ni) acc[mi][ni] = 0.0f;

  for (int kb = 0; kb < 1664; kb += 16) {
    const int k0 = k0base + kb;
    __syncthreads();
    {
      int m = tid;  // 0..127
      float4 v[4] = {{0,0,0,0},{0,0,0,0},{0,0,0,0},{0,0,0,0}};
      if (m < 120) {
        const float4* s = (const float4*)(spk + (size_t)m * 21632 + k0);
        v[0] = s[0]; v[1] = s[1]; v[2] = s[2]; v[3] = s[3];
      }
#pragma unroll
      for (int q = 0; q < 4; ++q) {
        slds[4 * q + 0][m] = v[q].x;
        slds[4 * q + 1][m] = v[q].y;
        slds[4 * q + 2][m] = v[q].z;
        slds[4 * q + 3][m] = v[q].w;
      }
    }
    for (int e = tid; e < 512; e += 128) {
      int n = e >> 4, kk = e & 15;
      wlds[kk][n] = fc1w[(size_t)(nt * 32 + n) * 21632 + k0 + kk];
    }
    __syncthreads();
#pragma unroll
    for (int kk = 0; kk < 16; ++kk) {
      const float4 wv = *(const float4*)&wlds[kk][tx * 4];
      const float4 s0 = *(const float4*)&slds[kk][ty * 8];
      const float4 s1 = *(const float4*)&slds[kk][ty * 8 + 4];
      float sv[8] = {s0.x, s0.y, s0.z, s0.w, s1.x, s1.y, s1.z, s1.w};
      float wz[4] = {wv.x, wv.y, wv.z, wv.w};
#pragma unroll
      for (int mi = 0; mi < 8; ++mi)
#pragma unroll
        for (int ni = 0; ni < 4; ++ni) acc[mi][ni] += sv[mi] * wz[ni];
    }
  }
#pragma unroll
  for (int mi = 0; mi < 8; ++mi) {
    int m = ty * 8 + mi;
    if (m < 120) {
      float4 o = {acc[mi][0], acc[mi][1], acc[mi][2], acc[mi][3]};
      *(float4*)&incp[((size_t)kc * 120 + m) * 512 + nt * 32 + tx * 4] = o;
    }
  }
}

// ---------------------------------------------------------------------------
// sequential membrane scan per (b,n): fire/reset, emit spike counts
// ---------------------------------------------------------------------------
__global__ __launch_bounds__(256) void k_scan(const float* __restrict__ incp,
                                              const float* __restrict__ fc1b,
                                              float* __restrict__ cnt) {
  int i = blockIdx.x * 256 + threadIdx.x;   // 0..2047
  int b = i >> 9, n = i & 511;
  float bias = fc1b[n];
  float m0 = 0.0f, c = 0.0f;
  for (int t = 0; t < 30; ++t) {
    int m = t * 4 + b;
    float s = bias;
    for (int kc = 0; kc < 13; ++kc) s += incp[((size_t)kc * 120 + m) * 512 + n];
    m0 += s;
    if (m0 > 1.0f) { c += 1.0f; m0 = 0.0f; }
  }
  cnt[i] = c;
}

// ---------------------------------------------------------------------------
// m1[b][o] = 30*fc2_b[o] + sum_n cnt[b][n]*fc2_w[o][n]
// ---------------------------------------------------------------------------
__global__ __launch_bounds__(256) void k_final(const float* __restrict__ cnt,
                                               const float* __restrict__ fc2w,
                                               const float* __restrict__ fc2b,
                                               float* __restrict__ out) {
  int o = threadIdx.x;
  if (o >= 216) return;
  int b = o / 54, oo = o - b * 54;
  const float* w = fc2w + (size_t)oo * 512;
  const float* c = cnt + (size_t)b * 512;
  float s = 0.0f;
  for (int n = 0; n < 512; ++n) s += c[n] * w[n];
  out[o] = s + 30.0f * fc2b[oo];
}

// ---------------------------------------------------------------------------
extern "C" void kernel_launch(void* const* d_in, const int* in_sizes, int n_in,
                              void* d_out, int out_size, void* d_ws, size_t ws_size,
                              hipStream_t stream) {
  (void)in_sizes; (void)n_in; (void)out_size; (void)ws_size;
  const float* x    = (const float*)d_in[0];
  const float* w1   = (const float*)d_in[1];
  const float* b1   = (const float*)d_in[2];
  const float* w2   = (const float*)d_in[3];
  const float* b2   = (const float*)d_in[4];
  const float* w3   = (const float*)d_in[5];
  const float* b3   = (const float*)d_in[6];
  const float* fc1w = (const float*)d_in[7];
  const float* fc1b = (const float*)d_in[8];
  const float* fc2w = (const float*)d_in[9];
  const float* fc2b = (const float*)d_in[10];
  float* out = (float*)d_out;
  float* ws  = (float*)d_ws;

  // workspace layout (floats); peak = 8,697,696 + 14,598,144 = 93.2 MB
  float* xp   = ws;                       // 8,697,696   (dead after conv1)
  float* h1   = ws + 8697696;             // 14,598,144  (dead after conv2)
  float* h2p  = ws;                       // 2 x 2,704,000 (reuses xp region)
  float* h2   = ws + 5408000;             // 2,704,000 (ends 8,112,000 < 8,697,696)
  float* h3p  = ws + 8697696;             // 4 x 86,528 (reuses h1 region)
  float* spk  = h3p + 4 * 86528;          // 2,595,840
  float* incp = spk + 2595840;            // 13 x 61,440 = 798,720
  float* cnt  = incp + 13 * 61440;        // 2,048

  // host-side threefry: seed 42 -> key (0,42); partitionable split
  SnnKeys keys;
  for (int t = 0; t < 30; ++t) {
    unsigned int a = 0u, bb = (unsigned int)t;
    tf2x32(0u, 42u, a, bb);
    keys.k0[t] = a; keys.k1[t] = bb;
  }

  k_pool <<<(POOL_N + 255) / 256, 256, 0, stream>>>(x, xp);
  k_conv1<<<dim3(41, 44),    256, 0, stream>>>(xp, w1, b1, h1);
  k_conv2<<<dim3(17, 40),    256, 0, stream>>>(h1, w2, h2p);
  k_h2fix<<<(2704000 + 255) / 256, 256, 0, stream>>>(h2p, b2, h2);
  k_conv3<<<dim3(4, 4, 32),  256, 0, stream>>>(h2, w3, h3p);
  k_spike<<<dim3(338, 30),   256, 0, stream>>>(h3p, b3, spk, keys);
  k_fc1  <<<dim3(16, 13), dim3(8, 16), 0, stream>>>(spk, fc1w, incp);
  k_scan <<<8, 256, 0, stream>>>(incp, fc1b, cnt);
  k_final<<<1, 256, 0, stream>>>(cnt, fc2w, fc2b, out);
}

// Round 4
// 1903.436 us; speedup vs baseline: 1.6822x; 1.2476x over previous
//
#include <hip/hip_runtime.h>
#include <stdint.h>

// ---------------------------------------------------------------------------
// JAX threefry2x32 (20 rounds), matching jax/_src/prng.py
// ---------------------------------------------------------------------------
struct SnnKeys { unsigned int k0[30]; unsigned int k1[30]; };

__host__ __device__ static inline void tf2x32(unsigned int k0, unsigned int k1,
                                              unsigned int& x0, unsigned int& x1) {
  unsigned int ks2 = k0 ^ k1 ^ 0x1BD11BDAu;
#define TF_RND(r) { x0 += x1; x1 = (x1 << (r)) | (x1 >> (32 - (r))); x1 ^= x0; }
  x0 += k0; x1 += k1;
  TF_RND(13) TF_RND(15) TF_RND(26) TF_RND(6)
  x0 += k1; x1 += ks2 + 1u;
  TF_RND(17) TF_RND(29) TF_RND(16) TF_RND(24)
  x0 += ks2; x1 += k0 + 2u;
  TF_RND(13) TF_RND(15) TF_RND(26) TF_RND(6)
  x0 += k0; x1 += k1 + 3u;
  TF_RND(17) TF_RND(29) TF_RND(16) TF_RND(24)
  x0 += k1; x1 += ks2 + 4u;
  TF_RND(13) TF_RND(15) TF_RND(26) TF_RND(6)
  x0 += ks2; x1 += k0 + 5u;
#undef TF_RND
}

// ---------------------------------------------------------------------------
// Stage 0: 2x2 average pool  x(4,24,602,602) -> xp(4,24,301,301)
// ---------------------------------------------------------------------------
#define POOL_N (4 * 24 * 301 * 301)

__global__ __launch_bounds__(256) void k_pool(const float* __restrict__ x,
                                              float* __restrict__ xp) {
  int i = blockIdx.x * 256 + threadIdx.x;
  if (i >= POOL_N) return;
  int j = i % 301;
  int rest = i / 301;
  int r = rest % 301;
  int bc = rest / 301;
  const float* src = x + ((size_t)bc * 602 + 2 * r) * 602 + 2 * j;
  float2 a = *(const float2*)src;
  float2 b = *(const float2*)(src + 602);
  xp[i] = 0.25f * ((a.x + a.y) + (b.x + b.y));
}

// ---------------------------------------------------------------------------
// weight transposes: [co][ci][kd][kh][kw] -> [ci][kd][kh][kw][co]
// ---------------------------------------------------------------------------
__global__ __launch_bounds__(256) void k_wt2(const float* __restrict__ w2,
                                             float* __restrict__ w2t) {
  int i = blockIdx.x * 256 + threadIdx.x;
  if (i >= 345600) return;
  int co = i & 31;
  int rest = i >> 5;            // ci*675 + kd*225 + k
  int ci = rest / 675;
  int k675 = rest - ci * 675;
  w2t[i] = w2[((size_t)co * 16 + ci) * 675 + k675];
}

__global__ __launch_bounds__(256) void k_wt3(const float* __restrict__ w3,
                                             float* __restrict__ w3t) {
  int i = blockIdx.x * 256 + threadIdx.x;
  if (i >= 345600) return;
  int co = i & 15;
  int rest = i >> 4;            // ci*675 + kd*225 + k
  int ci = rest / 675;
  int k675 = rest - ci * 675;
  w3t[i] = w3[((size_t)co * 32 + ci) * 675 + k675];
}

// ---------------------------------------------------------------------------
// conv1: xp(4,[1],24,301,301), w1(16,1,3,15,15), stride2 -> h1(4,16,11,144,144), relu
// grid (41 stile of 512 s, 44 b*d). 4 waves = 2 co-groups(8co) x 2 s-groups(256 s).
// Weights: wave-uniform scalar loads straight from w1 (SGPR, no LDS).
// ---------------------------------------------------------------------------
__global__ __launch_bounds__(256) void k_conv1(const float* __restrict__ xp,
                                               const float* __restrict__ w1,
                                               const float* __restrict__ b1,
                                               float* __restrict__ h1) {
  __shared__ alignas(16) float in_e[25 * 152];
  __shared__ alignas(16) float in_o[25 * 152];
  const int tid = threadIdx.x;
  const int wave = __builtin_amdgcn_readfirstlane(tid >> 6);
  const int lane = tid & 63;
  const int cog = wave >> 1, sg = wave & 1;
  const int cob = cog * 8;
  const int bz = blockIdx.y;
  const int b = bz / 11, d = bz % 11;
  const int s0 = blockIdx.x * 512;
  const int y0 = s0 / 144;

  int sq[4], be[4];
  bool vq[4];
#pragma unroll
  for (int q = 0; q < 4; ++q) {
    int s = s0 + sg * 256 + q * 64 + lane;
    vq[q] = (s < 20736);
    int sc = vq[q] ? s : 20735;
    int y = sc / 144, xx = sc - y * 144;
    sq[q] = s;
    be[q] = 2 * (y - y0) * 152 + xx;
  }

  float acc[8][4] = {};

  for (int kd = 0; kd < 3; ++kd) {
    __syncthreads();
    const int din = 2 * d + kd;
    const float* src = xp + (size_t)(b * 24 + din) * 90601;
    for (int i = tid; i < 25 * 301; i += 256) {
      int r = i / 301, c = i - r * 301;
      int gr = 2 * y0 + r;
      float v = (gr < 301) ? src[gr * 301 + c] : 0.0f;
      ((c & 1) ? in_o : in_e)[r * 152 + (c >> 1)] = v;
    }
    __syncthreads();
    const float* wp = w1 + cob * 675 + kd * 225;   // wp[c*675 + kh*15 + kw], uniform
    for (int kh = 0; kh < 15; ++kh) {
      float e[4][8], o[4][7];
#pragma unroll
      for (int q = 0; q < 4; ++q) {
        const float* pe = in_e + be[q] + kh * 152;
        const float* po = in_o + be[q] + kh * 152;
#pragma unroll
        for (int j = 0; j < 8; ++j) e[q][j] = pe[j];
#pragma unroll
        for (int j = 0; j < 7; ++j) o[q][j] = po[j];
      }
      const float* wk = wp + kh * 15;
#pragma unroll
      for (int j = 0; j < 8; ++j) {
#pragma unroll
        for (int c = 0; c < 8; ++c) {
          float wv = wk[c * 675 + 2 * j];
#pragma unroll
          for (int q = 0; q < 4; ++q) acc[c][q] += wv * e[q][j];
        }
      }
#pragma unroll
      for (int j = 0; j < 7; ++j) {
#pragma unroll
        for (int c = 0; c < 8; ++c) {
          float wv = wk[c * 675 + 2 * j + 1];
#pragma unroll
          for (int q = 0; q < 4; ++q) acc[c][q] += wv * o[q][j];
        }
      }
    }
  }
#pragma unroll
  for (int q = 0; q < 4; ++q) {
    if (vq[q]) {
#pragma unroll
      for (int c = 0; c < 8; ++c) {
        float v = acc[c][q] + b1[cob + c];
        h1[((size_t)(b * 16 + cob + c) * 11 + d) * 20736 + sq[q]] = fmaxf(v, 0.0f);
      }
    }
  }
}

// ---------------------------------------------------------------------------
// conv2: h1(4,16,11,144,144), w2t[ci][kd][k][32] -> partials (2 ci-groups)
// grid (17 stile of 256 s, 40 = b*d*cig). 4 waves = 4 co-groups(8co), shared s.
// Weights via SGPR s_load (consecutive co). Inputs via LDS reg-cached per kh.
// ---------------------------------------------------------------------------
__global__ __launch_bounds__(256) void k_conv2(const float* __restrict__ h1,
                                               const float* __restrict__ w2t,
                                               float* __restrict__ h2p) {
  __shared__ alignas(16) float in_e[23 * 72];
  __shared__ alignas(16) float in_o[23 * 72];
  const int tid = threadIdx.x;
  const int wave = __builtin_amdgcn_readfirstlane(tid >> 6);
  const int lane = tid & 63;
  const int cob = wave * 8;
  const int bz = blockIdx.y;
  const int cig = bz & 1;
  const int t5 = bz >> 1;
  const int b = t5 / 5, d = t5 % 5;
  const int s0 = blockIdx.x * 256;
  const int y0 = s0 / 65;

  int sq[4], be[4];
  bool vq[4];
#pragma unroll
  for (int q = 0; q < 4; ++q) {
    int s = s0 + q * 64 + lane;
    vq[q] = (s < 4225);
    int sc = vq[q] ? s : 4224;
    int y = sc / 65, xx = sc - y * 65;
    sq[q] = s;
    be[q] = 2 * (y - y0) * 72 + xx;
  }

  float acc[8][4] = {};

  for (int cil = 0; cil < 8; ++cil) {
    const int ci = cig * 8 + cil;
    for (int kd = 0; kd < 3; ++kd) {
      __syncthreads();
      const int din = 2 * d + kd;
      const float* src = h1 + (size_t)((b * 16 + ci) * 11 + din) * 20736;
      for (int i = tid; i < 23 * 36; i += 256) {
        int r = i / 36, c4 = i - r * 36;
        int gr = 2 * y0 + r;
        float4 v = {0.0f, 0.0f, 0.0f, 0.0f};
        if (gr < 144) v = *(const float4*)(src + gr * 144 + c4 * 4);
        *(float2*)&in_e[r * 72 + 2 * c4] = make_float2(v.x, v.z);
        *(float2*)&in_o[r * 72 + 2 * c4] = make_float2(v.y, v.w);
      }
      __syncthreads();
      const float* wkbase = w2t + (size_t)(ci * 3 + kd) * 225 * 32 + cob;  // uniform
      for (int kh = 0; kh < 15; ++kh) {
        float e[4][8], o[4][7];
#pragma unroll
        for (int q = 0; q < 4; ++q) {
          const float* pe = in_e + be[q] + kh * 72;
          const float* po = in_o + be[q] + kh * 72;
#pragma unroll
          for (int j = 0; j < 8; ++j) e[q][j] = pe[j];
#pragma unroll
          for (int j = 0; j < 7; ++j) o[q][j] = po[j];
        }
        const float* wr = wkbase + kh * 15 * 32;
#pragma unroll
        for (int j = 0; j < 8; ++j) {
#pragma unroll
          for (int c = 0; c < 8; ++c) {
            float wv = wr[(2 * j) * 32 + c];
#pragma unroll
            for (int q = 0; q < 4; ++q) acc[c][q] += wv * e[q][j];
          }
        }
#pragma unroll
        for (int j = 0; j < 7; ++j) {
#pragma unroll
          for (int c = 0; c < 8; ++c) {
            float wv = wr[(2 * j + 1) * 32 + c];
#pragma unroll
            for (int q = 0; q < 4; ++q) acc[c][q] += wv * o[q][j];
          }
        }
      }
    }
  }
#pragma unroll
  for (int q = 0; q < 4; ++q) {
    if (vq[q]) {
#pragma unroll
      for (int c = 0; c < 8; ++c) {
        h2p[(size_t)cig * 2704000 +
            ((size_t)(b * 32 + cob + c) * 5 + d) * 4225 + sq[q]] = acc[c][q];
      }
    }
  }
}

// combine conv2 partials + bias + relu
__global__ __launch_bounds__(256) void k_h2fix(const float* __restrict__ p,
                                               const float* __restrict__ b2,
                                               float* __restrict__ h2) {
  int i = blockIdx.x * 256 + threadIdx.x;
  if (i >= 2704000) return;
  int co = (i / 21125) & 31;               // 21125 = 5*65*65
  float v = p[i] + p[2704000 + i] + b2[co];
  h2[i] = fmaxf(v, 0.0f);
}

// ---------------------------------------------------------------------------
// conv3: h2(4,32,5,65,65), w3t[ci][kd][k][16] -> 16 ci-partials
// Flattened-s: plane 26*26=676 per (b,d). grid (2 stile of 512, 8 planes, 16 cig).
// 4 waves = 2 co-groups(8co) x 2 s-groups(256 s).
// ---------------------------------------------------------------------------
__global__ __launch_bounds__(256) void k_conv3(const float* __restrict__ h2,
                                               const float* __restrict__ w3t,
                                               float* __restrict__ h3p) {
  __shared__ alignas(16) float in_e[55 * 36];
  __shared__ alignas(16) float in_o[55 * 36];
  const int tid = threadIdx.x;
  const int wave = __builtin_amdgcn_readfirstlane(tid >> 6);
  const int lane = tid & 63;
  const int cog = wave >> 1, sg = wave & 1;
  const int cob = cog * 8;
  const int bz = blockIdx.y;               // b*2 + d
  const int b = bz >> 1, d = bz & 1;
  const int cig = blockIdx.z;              // 0..15 -> ci = 2*cig + cil
  const int s0 = blockIdx.x * 512;
  const int y0 = s0 / 26;

  int sq[4], be[4];
  bool vq[4];
#pragma unroll
  for (int q = 0; q < 4; ++q) {
    int s = s0 + sg * 256 + q * 64 + lane;
    vq[q] = (s < 676);
    int sc = vq[q] ? s : 675;
    int y = sc / 26, xx = sc - y * 26;
    sq[q] = s;
    be[q] = 2 * (y - y0) * 36 + xx;
  }

  float acc[8][4] = {};

  for (int cil = 0; cil < 2; ++cil) {
    const int ci = cig * 2 + cil;
    for (int kd = 0; kd < 3; ++kd) {
      __syncthreads();
      const int din = 2 * d + kd;
      const float* src = h2 + (size_t)((b * 32 + ci) * 5 + din) * 4225;
      for (int i = tid; i < 55 * 65; i += 256) {
        int r = i / 65, c = i - r * 65;
        int gr = 2 * y0 + r;
        float v = (gr < 65) ? src[gr * 65 + c] : 0.0f;
        ((c & 1) ? in_o : in_e)[r * 36 + (c >> 1)] = v;
      }
      __syncthreads();
      const float* wkbase = w3t + (size_t)(ci * 3 + kd) * 225 * 16 + cob;  // uniform
      for (int kh = 0; kh < 15; ++kh) {
        float e[4][8], o[4][7];
#pragma unroll
        for (int q = 0; q < 4; ++q) {
          const float* pe = in_e + be[q] + kh * 36;
          const float* po = in_o + be[q] + kh * 36;
#pragma unroll
          for (int j = 0; j < 8; ++j) e[q][j] = pe[j];
#pragma unroll
          for (int j = 0; j < 7; ++j) o[q][j] = po[j];
        }
        const float* wr = wkbase + kh * 15 * 16;
#pragma unroll
        for (int j = 0; j < 8; ++j) {
#pragma unroll
          for (int c = 0; c < 8; ++c) {
            float wv = wr[(2 * j) * 16 + c];
#pragma unroll
            for (int q = 0; q < 4; ++q) acc[c][q] += wv * e[q][j];
          }
        }
#pragma unroll
        for (int j = 0; j < 7; ++j) {
#pragma unroll
          for (int c = 0; c < 8; ++c) {
            float wv = wr[(2 * j + 1) * 16 + c];
#pragma unroll
            for (int q = 0; q < 4; ++q) acc[c][q] += wv * o[q][j];
          }
        }
      }
    }
  }
#pragma unroll
  for (int q = 0; q < 4; ++q) {
    if (vq[q]) {
#pragma unroll
      for (int c = 0; c < 8; ++c) {
        h3p[(size_t)cig * 86528 +
            ((size_t)(b * 16 + cob + c) * 2 + d) * 676 + sq[q]] = acc[c][q];
      }
    }
  }
}

// fold 16 conv3 partials + bias + relu -> prob = 0.5*x
__global__ __launch_bounds__(256) void k_h3fix(const float* __restrict__ h3p,
                                               const float* __restrict__ b3,
                                               float* __restrict__ prob) {
  int p = blockIdx.x * 256 + threadIdx.x;
  if (p >= 86528) return;
  int co = (p % 21632) / 1352;             // 1352 = 2*26*26
  float x = b3[co];
  for (int g = 0; g < 16; ++g) x += h3p[(size_t)g * 86528 + p];
  prob[p] = 0.5f * fmaxf(x, 0.0f);
}

// ---------------------------------------------------------------------------
// spikes: r = threefry-uniform; spk = (prob > r)
// grid (338, 30) block 256
// ---------------------------------------------------------------------------
__global__ __launch_bounds__(256) void k_spike(const float* __restrict__ prob,
                                               float* __restrict__ spk,
                                               SnnKeys keys) {
  int p = blockIdx.x * 256 + threadIdx.x;   // < 86528
  int t = blockIdx.y;
  float pr = prob[p];
  unsigned int x0 = 0u, x1 = (unsigned int)p;
  tf2x32(keys.k0[t], keys.k1[t], x0, x1);
  unsigned int bits = x0 ^ x1;              // partitionable 32-bit path
  float r = __uint_as_float((bits >> 9) | 0x3f800000u) - 1.0f;
  spk[(size_t)t * 86528 + p] = (pr > r) ? 1.0f : 0.0f;
}

// ---------------------------------------------------------------------------
// fc1 GEMM: inc_part[kc][m=(t*4+b)][n] = sum_k spk[m][k]*fc1_w[n][k]  (K split 13x1664)
// grid (16 nt, 13 kc), block (8,16)=128. thread tile 8m x 4n.
// ---------------------------------------------------------------------------
__global__ __launch_bounds__(128) void k_fc1(const float* __restrict__ spk,
                                             const float* __restrict__ fc1w,
                                             float* __restrict__ incp) {
  __shared__ alignas(16) float slds[16][128];
  __shared__ alignas(16) float wlds[16][32];
  const int tx = threadIdx.x;               // 0..7
  const int ty = threadIdx.y;               // 0..15
  const int tid = ty * 8 + tx;
  const int nt = blockIdx.x;                // 0..15
  const int kc = blockIdx.y;                // 0..12
  const int k0base = kc * 1664;

  float acc[8][4];
#pragma unroll
  for (int mi = 0; mi < 8; ++mi)
#pragma unroll
    for (int ni = 0; ni < 4; ++ni) acc[mi][ni] = 0.0f;

  for (int kb = 0; kb < 1664; kb += 16) {
    const int k0 = k0base + kb;
    __syncthreads();
    {
      int m = tid;  // 0..127
      float4 v[4] = {{0,0,0,0},{0,0,0,0},{0,0,0,0},{0,0,0,0}};
      if (m < 120) {
        const float4* s = (const float4*)(spk + (size_t)m * 21632 + k0);
        v[0] = s[0]; v[1] = s[1]; v[2] = s[2]; v[3] = s[3];
      }
#pragma unroll
      for (int q = 0; q < 4; ++q) {
        slds[4 * q + 0][m] = v[q].x;
        slds[4 * q + 1][m] = v[q].y;
        slds[4 * q + 2][m] = v[q].z;
        slds[4 * q + 3][m] = v[q].w;
      }
    }
    for (int e = tid; e < 512; e += 128) {
      int n = e >> 4, kk = e & 15;
      wlds[kk][n] = fc1w[(size_t)(nt * 32 + n) * 21632 + k0 + kk];
    }
    __syncthreads();
#pragma unroll
    for (int kk = 0; kk < 16; ++kk) {
      const float4 wv = *(const float4*)&wlds[kk][tx * 4];
      const float4 s0 = *(const float4*)&slds[kk][ty * 8];
      const float4 s1 = *(const float4*)&slds[kk][ty * 8 + 4];
      float sv[8] = {s0.x, s0.y, s0.z, s0.w, s1.x, s1.y, s1.z, s1.w};
      float wz[4] = {wv.x, wv.y, wv.z, wv.w};
#pragma unroll
      for (int mi = 0; mi < 8; ++mi)
#pragma unroll
        for (int ni = 0; ni < 4; ++ni) acc[mi][ni] += sv[mi] * wz[ni];
    }
  }
#pragma unroll
  for (int mi = 0; mi < 8; ++mi) {
    int m = ty * 8 + mi;
    if (m < 120) {
      float4 o = {acc[mi][0], acc[mi][1], acc[mi][2], acc[mi][3]};
      *(float4*)&incp[((size_t)kc * 120 + m) * 512 + nt * 32 + tx * 4] = o;
    }
  }
}

// ---------------------------------------------------------------------------
// sequential membrane scan per (b,n): fire/reset, emit spike counts
// ---------------------------------------------------------------------------
__global__ __launch_bounds__(256) void k_scan(const float* __restrict__ incp,
                                              const float* __restrict__ fc1b,
                                              float* __restrict__ cnt) {
  int i = blockIdx.x * 256 + threadIdx.x;   // 0..2047
  int b = i >> 9, n = i & 511;
  float bias = fc1b[n];
  float m0 = 0.0f, c = 0.0f;
  for (int t = 0; t < 30; ++t) {
    int m = t * 4 + b;
    float s = bias;
    for (int kc = 0; kc < 13; ++kc) s += incp[((size_t)kc * 120 + m) * 512 + n];
    m0 += s;
    if (m0 > 1.0f) { c += 1.0f; m0 = 0.0f; }
  }
  cnt[i] = c;
}

// ---------------------------------------------------------------------------
// m1[b][o] = 30*fc2_b[o] + sum_n cnt[b][n]*fc2_w[o][n]
// ---------------------------------------------------------------------------
__global__ __launch_bounds__(256) void k_final(const float* __restrict__ cnt,
                                               const float* __restrict__ fc2w,
                                               const float* __restrict__ fc2b,
                                               float* __restrict__ out) {
  int o = threadIdx.x;
  if (o >= 216) return;
  int b = o / 54, oo = o - b * 54;
  const float* w = fc2w + (size_t)oo * 512;
  const float* c = cnt + (size_t)b * 512;
  float s = 0.0f;
  for (int n = 0; n < 512; ++n) s += c[n] * w[n];
  out[o] = s + 30.0f * fc2b[oo];
}

// ---------------------------------------------------------------------------
extern "C" void kernel_launch(void* const* d_in, const int* in_sizes, int n_in,
                              void* d_out, int out_size, void* d_ws, size_t ws_size,
                              hipStream_t stream) {
  (void)in_sizes; (void)n_in; (void)out_size; (void)ws_size;
  const float* x    = (const float*)d_in[0];
  const float* w1   = (const float*)d_in[1];
  const float* b1   = (const float*)d_in[2];
  const float* w2   = (const float*)d_in[3];
  const float* b2   = (const float*)d_in[4];
  const float* w3   = (const float*)d_in[5];
  const float* b3   = (const float*)d_in[6];
  const float* fc1w = (const float*)d_in[7];
  const float* fc1b = (const float*)d_in[8];
  const float* fc2w = (const float*)d_in[9];
  const float* fc2b = (const float*)d_in[10];
  float* out = (float*)d_out;
  float* ws  = (float*)d_ws;

  // workspace layout (floats); peak = xp+h1 = 23,295,840 fl = 93.2 MB (unchanged)
  float* xp   = ws;                       // [0 .. 8,697,696)            dead after conv1
  float* h1   = ws + 8697696;             // [8,697,696 .. 23,295,840)   dead after conv2
  float* w2t  = ws + 8112000;             // 345,600 (in dead xp tail; written after conv1)
  float* h2p  = ws;                       // 2 x 2,704,000 = [0 .. 5,408,000)
  float* h2   = ws + 5408000;             // [5,408,000 .. 8,112,000)
  float* w3t  = ws;                       // 345,600 (in dead h2p; written after h2fix)
  float* h3p  = ws + 8697696;             // 16 x 86,528 = 1,384,448 (dead h1)
  float* prob = h3p + 16 * 86528;         // 86,528
  float* spk  = prob + 86528;             // 2,595,840
  float* incp = spk + 2595840;            // 13 x 61,440 = 798,720
  float* cnt  = incp + 13 * 61440;        // 2,048 (end 13,565,280 < 23,295,840)

  // host-side threefry: seed 42 -> key (0,42); partitionable split
  SnnKeys keys;
  for (int t = 0; t < 30; ++t) {
    unsigned int a = 0u, bb = (unsigned int)t;
    tf2x32(0u, 42u, a, bb);
    keys.k0[t] = a; keys.k1[t] = bb;
  }

  k_pool <<<(POOL_N + 255) / 256, 256, 0, stream>>>(x, xp);
  k_conv1<<<dim3(41, 44),    256, 0, stream>>>(xp, w1, b1, h1);
  k_wt2  <<<1350, 256, 0, stream>>>(w2, w2t);
  k_conv2<<<dim3(17, 40),    256, 0, stream>>>(h1, w2t, h2p);
  k_h2fix<<<(2704000 + 255) / 256, 256, 0, stream>>>(h2p, b2, h2);
  k_wt3  <<<1350, 256, 0, stream>>>(w3, w3t);
  k_conv3<<<dim3(2, 8, 16),  256, 0, stream>>>(h2, w3t, h3p);
  k_h3fix<<<338, 256, 0, stream>>>(h3p, b3, prob);
  k_spike<<<dim3(338, 30),   256, 0, stream>>>(prob, spk, keys);
  k_fc1  <<<dim3(16, 13), dim3(8, 16), 0, stream>>>(spk, fc1w, incp);
  k_scan <<<8, 256, 0, stream>>>(incp, fc1b, cnt);
  k_final<<<1, 256, 0, stream>>>(cnt, fc2w, fc2b, out);
}